// Round 2
// baseline (1593.105 us; speedup 1.0000x reference)
//
#include <hip/hip_runtime.h>
#include <math.h>

#define ROWS 32
#define NTHREADS 256

// One 73.7 KB LDS region, reused phase-by-phase:
//   phase 1: xs[2][128][36]  fp64 transposed x chunk (GEMM1 double-buffer)
//   phase 2: a_t[256][36]    fp64 transposed relu(LN(h)) (GEMM2/GEMM3 input)
//   phase 3: h2t[128][36] + lgt[32][66]  (GEMM4 input, logits)
struct alignas(16) SMem {
    union {
        double xs[2][128][36];
        double a_t[256][36];
        struct { double h2t[128][36]; double lgt[32][66]; } p3;
    } u;
};

__global__ __launch_bounds__(NTHREADS, 2)
void gating_fused_f64(const float* __restrict__ x,
                      const float* __restrict__ W_in, const float* __restrict__ b_in,
                      const float* __restrict__ ln1_g, const float* __restrict__ ln1_b,
                      const float* __restrict__ W1,   const float* __restrict__ b1,
                      const float* __restrict__ ln2_g, const float* __restrict__ ln2_b,
                      const float* __restrict__ W2,   const float* __restrict__ b2,
                      const float* __restrict__ Wo,   const float* __restrict__ bo,
                      const float* __restrict__ temp,
                      float* __restrict__ out)
{
    __shared__ SMem sm;
    const int tid = threadIdx.x;
    const int cg  = tid & 31;    // column-group lane (0..31)
    const int rg  = tid >> 5;    // row group (0..7)
    const int r0  = rg << 2;     // 4 rows per thread
    const int row_base = blockIdx.x * ROWS;

    // ================= GEMM1: h0 = relu(x @ W_in + b_in), fp64 acc =========
    const int c0 = cg << 3;   // 8 cols per thread (H1=256)
    double acc[8][4];
    #pragma unroll
    for (int i = 0; i < 8; ++i)
        #pragma unroll
        for (int j = 0; j < 4; ++j) acc[i][j] = 0.0;

    // stage chunk 0: 32 rows x 128 k, transposed [k][r], converted to fp64
    #pragma unroll
    for (int it = 0; it < 4; ++it) {
        int idx = tid + it * 256;
        int rr = idx >> 5, k4 = idx & 31;
        const float4 v = *reinterpret_cast<const float4*>(
            x + (size_t)(row_base + rr) * 1024 + k4 * 4);
        sm.u.xs[0][k4 * 4 + 0][rr] = (double)v.x;
        sm.u.xs[0][k4 * 4 + 1][rr] = (double)v.y;
        sm.u.xs[0][k4 * 4 + 2][rr] = (double)v.z;
        sm.u.xs[0][k4 * 4 + 3][rr] = (double)v.w;
    }

    for (int ch = 0; ch < 8; ++ch) {
        __syncthreads();
        // issue next chunk's global loads early (hide HBM under compute)
        float4 vnext[4];
        if (ch < 7) {
            #pragma unroll
            for (int it = 0; it < 4; ++it) {
                int idx = tid + it * 256;
                int rr = idx >> 5, k4 = idx & 31;
                vnext[it] = *reinterpret_cast<const float4*>(
                    x + (size_t)(row_base + rr) * 1024 + (ch + 1) * 128 + k4 * 4);
            }
        }
        const int buf = ch & 1;
        const float* wbase = W_in + (size_t)ch * 128 * 256 + c0;
        #pragma unroll 2
        for (int k = 0; k < 128; ++k) {
            const double2 x01 = *reinterpret_cast<const double2*>(&sm.u.xs[buf][k][r0]);
            const double2 x23 = *reinterpret_cast<const double2*>(&sm.u.xs[buf][k][r0 + 2]);
            const float4 w0 = *reinterpret_cast<const float4*>(wbase + (size_t)k * 256);
            const float4 w1 = *reinterpret_cast<const float4*>(wbase + (size_t)k * 256 + 4);
            const double xr[4] = {x01.x, x01.y, x23.x, x23.y};
            const double wc[8] = {(double)w0.x, (double)w0.y, (double)w0.z, (double)w0.w,
                                  (double)w1.x, (double)w1.y, (double)w1.z, (double)w1.w};
            #pragma unroll
            for (int i = 0; i < 8; ++i)
                #pragma unroll
                for (int j = 0; j < 4; ++j)
                    acc[i][j] = fma(wc[i], xr[j], acc[i][j]);
        }
        if (ch < 7) {
            #pragma unroll
            for (int it = 0; it < 4; ++it) {
                int idx = tid + it * 256;
                int rr = idx >> 5, k4 = idx & 31;
                sm.u.xs[buf ^ 1][k4 * 4 + 0][rr] = (double)vnext[it].x;
                sm.u.xs[buf ^ 1][k4 * 4 + 1][rr] = (double)vnext[it].y;
                sm.u.xs[buf ^ 1][k4 * 4 + 2][rr] = (double)vnext[it].z;
                sm.u.xs[buf ^ 1][k4 * 4 + 3][rr] = (double)vnext[it].w;
            }
        }
    }

    { // + b_in, relu (fp64)
        #pragma unroll
        for (int i = 0; i < 8; ++i) {
            const double bi = (double)b_in[c0 + i];
            #pragma unroll
            for (int j = 0; j < 4; ++j)
                acc[i][j] = fmax(acc[i][j] + bi, 0.0);
        }
    }

    // all xs reads done; a_t overlays xs — barrier before writing a_t
    __syncthreads();

    // ============== LN1 -> relu -> a_t (transposed [c][r], fp64) ==========
    {
        double s[4] = {0, 0, 0, 0}, q[4] = {0, 0, 0, 0};
        #pragma unroll
        for (int i = 0; i < 8; ++i)
            #pragma unroll
            for (int j = 0; j < 4; ++j) { s[j] += acc[i][j]; q[j] += acc[i][j] * acc[i][j]; }
        #pragma unroll
        for (int m = 1; m < 32; m <<= 1) {
            #pragma unroll
            for (int j = 0; j < 4; ++j) {
                s[j] += __shfl_xor(s[j], m);
                q[j] += __shfl_xor(q[j], m);
            }
        }
        double mu[4], rs[4];
        #pragma unroll
        for (int j = 0; j < 4; ++j) {
            mu[j] = s[j] * (1.0 / 256.0);
            double var = q[j] * (1.0 / 256.0) - mu[j] * mu[j];
            rs[j] = 1.0 / sqrt(var + 1e-5);
        }
        #pragma unroll
        for (int i = 0; i < 8; ++i) {
            const double gg = (double)ln1_g[c0 + i];
            const double bb = (double)ln1_b[c0 + i];
            double a0 = fmax((acc[i][0] - mu[0]) * rs[0] * gg + bb, 0.0);
            double a1 = fmax((acc[i][1] - mu[1]) * rs[1] * gg + bb, 0.0);
            double a2 = fmax((acc[i][2] - mu[2]) * rs[2] * gg + bb, 0.0);
            double a3 = fmax((acc[i][3] - mu[3]) * rs[3] * gg + bb, 0.0);
            double2* p = reinterpret_cast<double2*>(&sm.u.a_t[c0 + i][r0]);
            p[0] = make_double2(a0, a1);
            p[1] = make_double2(a2, a3);
        }
    }
    __syncthreads();

    // ================= GEMM2: h1 = a @ W1 + b1 + h0 (fp64) =================
    {
        double acc2[8][4];
        #pragma unroll
        for (int i = 0; i < 8; ++i)
            #pragma unroll
            for (int j = 0; j < 4; ++j) acc2[i][j] = 0.0;
        #pragma unroll 2
        for (int k = 0; k < 256; ++k) {
            const double2 a01 = *reinterpret_cast<const double2*>(&sm.u.a_t[k][r0]);
            const double2 a23 = *reinterpret_cast<const double2*>(&sm.u.a_t[k][r0 + 2]);
            const float4 w0 = *reinterpret_cast<const float4*>(W1 + (size_t)k * 256 + c0);
            const float4 w1 = *reinterpret_cast<const float4*>(W1 + (size_t)k * 256 + c0 + 4);
            const double ar[4] = {a01.x, a01.y, a23.x, a23.y};
            const double wc[8] = {(double)w0.x, (double)w0.y, (double)w0.z, (double)w0.w,
                                  (double)w1.x, (double)w1.y, (double)w1.z, (double)w1.w};
            #pragma unroll
            for (int i = 0; i < 8; ++i)
                #pragma unroll
                for (int j = 0; j < 4; ++j)
                    acc2[i][j] = fma(wc[i], ar[j], acc2[i][j]);
        }
        __syncthreads();   // all a_t reads complete before LN2 overwrites
        #pragma unroll
        for (int i = 0; i < 8; ++i) {
            const double bv = (double)b1[c0 + i];
            #pragma unroll
            for (int j = 0; j < 4; ++j)
                acc[i][j] = acc2[i][j] + bv + acc[i][j];   // acc := h1
        }
    }

    // ============== LN2 -> relu -> a_t (fp64) ==============
    {
        double s[4] = {0, 0, 0, 0}, q[4] = {0, 0, 0, 0};
        #pragma unroll
        for (int i = 0; i < 8; ++i)
            #pragma unroll
            for (int j = 0; j < 4; ++j) { s[j] += acc[i][j]; q[j] += acc[i][j] * acc[i][j]; }
        #pragma unroll
        for (int m = 1; m < 32; m <<= 1) {
            #pragma unroll
            for (int j = 0; j < 4; ++j) {
                s[j] += __shfl_xor(s[j], m);
                q[j] += __shfl_xor(q[j], m);
            }
        }
        double mu[4], rs[4];
        #pragma unroll
        for (int j = 0; j < 4; ++j) {
            mu[j] = s[j] * (1.0 / 256.0);
            double var = q[j] * (1.0 / 256.0) - mu[j] * mu[j];
            rs[j] = 1.0 / sqrt(var + 1e-5);
        }
        #pragma unroll
        for (int i = 0; i < 8; ++i) {
            const double gg = (double)ln2_g[c0 + i];
            const double bb = (double)ln2_b[c0 + i];
            double a0 = fmax((acc[i][0] - mu[0]) * rs[0] * gg + bb, 0.0);
            double a1 = fmax((acc[i][1] - mu[1]) * rs[1] * gg + bb, 0.0);
            double a2 = fmax((acc[i][2] - mu[2]) * rs[2] * gg + bb, 0.0);
            double a3 = fmax((acc[i][3] - mu[3]) * rs[3] * gg + bb, 0.0);
            double2* p = reinterpret_cast<double2*>(&sm.u.a_t[c0 + i][r0]);
            p[0] = make_double2(a0, a1);
            p[1] = make_double2(a2, a3);
        }
    }
    __syncthreads();

    // ================= GEMM3: h2 = a2 @ W2 + b2  ([32,128], fp64) ==========
    {
        const int c3 = cg << 2;   // 4 cols per thread (H2=128)
        double acc3[4][4];
        #pragma unroll
        for (int i = 0; i < 4; ++i)
            #pragma unroll
            for (int j = 0; j < 4; ++j) acc3[i][j] = 0.0;
        #pragma unroll 2
        for (int k = 0; k < 256; ++k) {
            const double2 a01 = *reinterpret_cast<const double2*>(&sm.u.a_t[k][r0]);
            const double2 a23 = *reinterpret_cast<const double2*>(&sm.u.a_t[k][r0 + 2]);
            const float4 w = *reinterpret_cast<const float4*>(W2 + (size_t)k * 128 + c3);
            const double ar[4] = {a01.x, a01.y, a23.x, a23.y};
            const double wc[4] = {(double)w.x, (double)w.y, (double)w.z, (double)w.w};
            #pragma unroll
            for (int i = 0; i < 4; ++i)
                #pragma unroll
                for (int j = 0; j < 4; ++j)
                    acc3[i][j] = fma(wc[i], ar[j], acc3[i][j]);
        }
        __syncthreads();   // all a_t reads complete; h2t overlays a_t
        #pragma unroll
        for (int i = 0; i < 4; ++i) {
            const double bv = (double)b2[c3 + i];
            double2* p = reinterpret_cast<double2*>(&sm.u.p3.h2t[c3 + i][r0]);
            p[0] = make_double2(acc3[i][0] + bv, acc3[i][1] + bv);
            p[1] = make_double2(acc3[i][2] + bv, acc3[i][3] + bv);
        }
    }
    __syncthreads();

    // ================= GEMM4: logits = (h2 @ W_out + b_out)/T (fp64) =======
    {
        const int c4 = cg << 1;   // 2 cols per thread (E=64)
        double acc4[2][4];
        #pragma unroll
        for (int i = 0; i < 2; ++i)
            #pragma unroll
            for (int j = 0; j < 4; ++j) acc4[i][j] = 0.0;
        #pragma unroll 2
        for (int k = 0; k < 128; ++k) {
            const double2 h01 = *reinterpret_cast<const double2*>(&sm.u.p3.h2t[k][r0]);
            const double2 h23 = *reinterpret_cast<const double2*>(&sm.u.p3.h2t[k][r0 + 2]);
            const float2 w = *reinterpret_cast<const float2*>(Wo + (size_t)k * 64 + c4);
            const double hr[4] = {h01.x, h01.y, h23.x, h23.y};
            const double w0 = (double)w.x, w1 = (double)w.y;
            #pragma unroll
            for (int j = 0; j < 4; ++j) {
                acc4[0][j] = fma(w0, hr[j], acc4[0][j]);
                acc4[1][j] = fma(w1, hr[j], acc4[1][j]);
            }
        }
        const double T = (double)temp[0];
        const double bo0 = (double)bo[c4], bo1 = (double)bo[c4 + 1];
        #pragma unroll
        for (int j = 0; j < 4; ++j) {
            sm.u.p3.lgt[r0 + j][c4]     = (acc4[0][j] + bo0) / T;
            sm.u.p3.lgt[r0 + j][c4 + 1] = (acc4[1][j] + bo1) / T;
        }
    }
    __syncthreads();

    // ================= softmax + top-8 per row (fp64 ranking) ==============
    {
        const int wave = tid >> 6;
        const int lane = tid & 63;
        float* out_topp = out;
        float* out_topi = out + (size_t)65536 * 8;
        float* out_gp   = out + (size_t)65536 * 16;

        for (int j = 0; j < 8; ++j) {
            const int r = wave * 8 + j;
            double v = sm.u.p3.lgt[r][lane];
            double m = v;
            #pragma unroll
            for (int mk = 32; mk >= 1; mk >>= 1) m = fmax(m, __shfl_xor(m, mk));
            double p = exp(v - m);
            double ssum = p;
            #pragma unroll
            for (int mk = 32; mk >= 1; mk >>= 1) ssum += __shfl_xor(ssum, mk);
            double gp = p / ssum;
            out_gp[(size_t)(row_base + r) * 64 + lane] = (float)gp;

            // iterative argmax top-8 on fp64 probs, ties -> lowest index
            double pv = gp;
            int    pi = lane;
            double sum8 = 0.0, myv = 0.0;
            int    myi = 0;
            #pragma unroll
            for (int t = 0; t < 8; ++t) {
                double cv = pv;
                int    ci = pi;
                #pragma unroll
                for (int mk = 32; mk >= 1; mk >>= 1) {
                    double ov = __shfl_xor(cv, mk);
                    int    oi = __shfl_xor(ci, mk);
                    if (ov > cv || (ov == cv && oi < ci)) { cv = ov; ci = oi; }
                }
                sum8 += cv;
                if (lane == t)  { myv = cv; myi = ci; }
                if (lane == ci) pv = -1.0;
            }
            if (lane < 8) {
                out_topp[(size_t)(row_base + r) * 8 + lane] = (float)(myv / sum8);
                out_topi[(size_t)(row_base + r) * 8 + lane] = (float)myi;
            }
        }
    }
}

extern "C" void kernel_launch(void* const* d_in, const int* in_sizes, int n_in,
                              void* d_out, int out_size, void* d_ws, size_t ws_size,
                              hipStream_t stream) {
    const float* x     = (const float*)d_in[0];
    const float* W_in  = (const float*)d_in[1];
    const float* b_in  = (const float*)d_in[2];
    const float* ln1_g = (const float*)d_in[3];
    const float* ln1_b = (const float*)d_in[4];
    const float* W1    = (const float*)d_in[5];
    const float* b1    = (const float*)d_in[6];
    const float* ln2_g = (const float*)d_in[7];
    const float* ln2_b = (const float*)d_in[8];
    const float* W2    = (const float*)d_in[9];
    const float* b2    = (const float*)d_in[10];
    const float* Wo    = (const float*)d_in[11];
    const float* bo    = (const float*)d_in[12];
    const float* temp  = (const float*)d_in[13];

    gating_fused_f64<<<dim3(65536 / ROWS), dim3(NTHREADS), 0, stream>>>(
        x, W_in, b_in, ln1_g, ln1_b, W1, b1, ln2_g, ln2_b, W2, b2, Wo, bo, temp,
        (float*)d_out);
}

// Round 3
// 1081.910 us; speedup vs baseline: 1.4725x; 1.4725x over previous
//
#include <hip/hip_runtime.h>
#include <math.h>

#define ROWS 32
#define NTHREADS 256
#define TAU 2e-5f

// LDS: one 36.9 KB union reused phase-by-phase (-> 4 blocks/CU):
//  phase1: xs[2][128][36]  fp32 transposed x chunk (GEMM1 dbuf), k-permuted rows
//  phase2: a_t[256][36]    fp32 transposed relu(LN(h)) (GEMM2/3 input), c-permuted
//  phase3: h2t[128][36] + lgt[32][66]
//  rescue: fp64 per-row arrays
struct alignas(16) SMem {
    union {
        float xs[2][128][36];
        float a_t[256][36];
        struct { float h2t[128][36]; float lgt[32][66]; } p3;
        struct { double hd0[256]; double a1d[256]; double h2d[128]; double lgd[64]; } rs;
    } u;
};

__global__ __launch_bounds__(NTHREADS, 4)
void gating_fused_f32(const float* __restrict__ x,
                      const float* __restrict__ W_in, const float* __restrict__ b_in,
                      const float* __restrict__ ln1_g, const float* __restrict__ ln1_b,
                      const float* __restrict__ W1,   const float* __restrict__ b1,
                      const float* __restrict__ ln2_g, const float* __restrict__ ln2_b,
                      const float* __restrict__ W2,   const float* __restrict__ b2,
                      const float* __restrict__ Wo,   const float* __restrict__ bo,
                      const float* __restrict__ temp,
                      float* __restrict__ out)
{
    __shared__ SMem sm;
    __shared__ unsigned cmask;
    const int tid = threadIdx.x;
    const int cg  = tid & 31;    // column-group lane (0..31)
    const int rg  = tid >> 5;    // row group (0..7)
    const int r0  = rg << 2;     // 4 rows per thread
    const int row_base = blockIdx.x * ROWS;
    if (tid == 0) cmask = 0;

    float* out_topp = out;
    float* out_topi = out + (size_t)65536 * 8;
    float* out_gp   = out + (size_t)65536 * 16;

    // Column ownership (H1=256): i=0..3 -> cols 4cg+i ; i=4..7 -> cols 128+4cg+(i-4)
    // ============ GEMM1: h0 = relu(x @ W_in + b_in), fp32 ============
    float acc[8][4];
    #pragma unroll
    for (int i = 0; i < 8; ++i)
        #pragma unroll
        for (int j = 0; j < 4; ++j) acc[i][j] = 0.f;

    // stage chunk 0: rows of x transposed into xs with k-permutation p = a + 32*j
    #pragma unroll
    for (int it = 0; it < 4; ++it) {
        int idx = tid + it * 256;
        int rr = idx >> 5, a = idx & 31;
        const float4 v = *reinterpret_cast<const float4*>(
            x + (size_t)(row_base + rr) * 1024 + a * 4);
        sm.u.xs[0][a +  0][rr] = v.x;
        sm.u.xs[0][a + 32][rr] = v.y;
        sm.u.xs[0][a + 64][rr] = v.z;
        sm.u.xs[0][a + 96][rr] = v.w;
    }

    for (int ch = 0; ch < 8; ++ch) {
        __syncthreads();
        float4 vnext[4];
        if (ch < 7) {
            #pragma unroll
            for (int it = 0; it < 4; ++it) {
                int idx = tid + it * 256;
                int rr = idx >> 5, a = idx & 31;
                vnext[it] = *reinterpret_cast<const float4*>(
                    x + (size_t)(row_base + rr) * 1024 + (ch + 1) * 128 + a * 4);
            }
        }
        const int buf = ch & 1;
        #pragma unroll 4
        for (int p = 0; p < 128; ++p) {
            const float4 xv = *reinterpret_cast<const float4*>(&sm.u.xs[buf][p][r0]);
            const int k = ((p & 31) << 2) | (p >> 5);   // inverse permutation
            const float* wb = W_in + (size_t)(ch * 128 + k) * 256;
            const float4 w0 = *reinterpret_cast<const float4*>(wb + 4 * cg);
            const float4 w1 = *reinterpret_cast<const float4*>(wb + 128 + 4 * cg);
            const float xr[4] = {xv.x, xv.y, xv.z, xv.w};
            const float wc[8] = {w0.x, w0.y, w0.z, w0.w, w1.x, w1.y, w1.z, w1.w};
            #pragma unroll
            for (int i = 0; i < 8; ++i)
                #pragma unroll
                for (int j = 0; j < 4; ++j)
                    acc[i][j] = fmaf(wc[i], xr[j], acc[i][j]);
        }
        if (ch < 7) {
            #pragma unroll
            for (int it = 0; it < 4; ++it) {
                int idx = tid + it * 256;
                int rr = idx >> 5, a = idx & 31;
                sm.u.xs[buf ^ 1][a +  0][rr] = vnext[it].x;
                sm.u.xs[buf ^ 1][a + 32][rr] = vnext[it].y;
                sm.u.xs[buf ^ 1][a + 64][rr] = vnext[it].z;
                sm.u.xs[buf ^ 1][a + 96][rr] = vnext[it].w;
            }
        }
    }

    { // + b_in, relu
        const float4 bi0 = *reinterpret_cast<const float4*>(b_in + 4 * cg);
        const float4 bi1 = *reinterpret_cast<const float4*>(b_in + 128 + 4 * cg);
        const float bi[8] = {bi0.x, bi0.y, bi0.z, bi0.w, bi1.x, bi1.y, bi1.z, bi1.w};
        #pragma unroll
        for (int i = 0; i < 8; ++i)
            #pragma unroll
            for (int j = 0; j < 4; ++j)
                acc[i][j] = fmaxf(acc[i][j] + bi[i], 0.f);
    }

    __syncthreads();   // xs dead; a_t overlays

    // ===== LN1 -> relu -> a_t (transposed, col-permuted q = g + 64*jj) =====
    {
        float s[4] = {0, 0, 0, 0}, q[4] = {0, 0, 0, 0};
        #pragma unroll
        for (int i = 0; i < 8; ++i)
            #pragma unroll
            for (int j = 0; j < 4; ++j) { s[j] += acc[i][j]; q[j] += acc[i][j] * acc[i][j]; }
        #pragma unroll
        for (int m = 1; m < 32; m <<= 1) {
            #pragma unroll
            for (int j = 0; j < 4; ++j) {
                s[j] += __shfl_xor(s[j], m);
                q[j] += __shfl_xor(q[j], m);
            }
        }
        float mu[4], rs[4];
        #pragma unroll
        for (int j = 0; j < 4; ++j) {
            mu[j] = s[j] * (1.f / 256.f);
            float var = q[j] * (1.f / 256.f) - mu[j] * mu[j];
            rs[j] = rsqrtf(var + 1e-5f);
        }
        const float4 g0 = *reinterpret_cast<const float4*>(ln1_g + 4 * cg);
        const float4 g1 = *reinterpret_cast<const float4*>(ln1_g + 128 + 4 * cg);
        const float4 e0 = *reinterpret_cast<const float4*>(ln1_b + 4 * cg);
        const float4 e1 = *reinterpret_cast<const float4*>(ln1_b + 128 + 4 * cg);
        const float gg[8] = {g0.x, g0.y, g0.z, g0.w, g1.x, g1.y, g1.z, g1.w};
        const float bb[8] = {e0.x, e0.y, e0.z, e0.w, e1.x, e1.y, e1.z, e1.w};
        #pragma unroll
        for (int h = 0; h < 2; ++h)
            #pragma unroll
            for (int jj = 0; jj < 4; ++jj) {
                const int i = h * 4 + jj;
                const int qrow = (cg + 32 * h) + 64 * jj;
                float4 av;
                av.x = fmaxf((acc[i][0] - mu[0]) * rs[0] * gg[i] + bb[i], 0.f);
                av.y = fmaxf((acc[i][1] - mu[1]) * rs[1] * gg[i] + bb[i], 0.f);
                av.z = fmaxf((acc[i][2] - mu[2]) * rs[2] * gg[i] + bb[i], 0.f);
                av.w = fmaxf((acc[i][3] - mu[3]) * rs[3] * gg[i] + bb[i], 0.f);
                *reinterpret_cast<float4*>(&sm.u.a_t[qrow][r0]) = av;
            }
    }
    __syncthreads();

    // ============ GEMM2: h1 = a @ W1 + b1 + h0 ============
    {
        float acc2[8][4];
        #pragma unroll
        for (int i = 0; i < 8; ++i)
            #pragma unroll
            for (int j = 0; j < 4; ++j) acc2[i][j] = 0.f;
        #pragma unroll 4
        for (int q = 0; q < 256; ++q) {
            const float4 av = *reinterpret_cast<const float4*>(&sm.u.a_t[q][r0]);
            const int k = ((q & 63) << 2) | (q >> 6);
            const float* wb = W1 + (size_t)k * 256;
            const float4 w0 = *reinterpret_cast<const float4*>(wb + 4 * cg);
            const float4 w1 = *reinterpret_cast<const float4*>(wb + 128 + 4 * cg);
            const float ar[4] = {av.x, av.y, av.z, av.w};
            const float wc[8] = {w0.x, w0.y, w0.z, w0.w, w1.x, w1.y, w1.z, w1.w};
            #pragma unroll
            for (int i = 0; i < 8; ++i)
                #pragma unroll
                for (int j = 0; j < 4; ++j)
                    acc2[i][j] = fmaf(wc[i], ar[j], acc2[i][j]);
        }
        __syncthreads();   // a_t reads done before LN2 overwrites
        const float4 c10 = *reinterpret_cast<const float4*>(b1 + 4 * cg);
        const float4 c11 = *reinterpret_cast<const float4*>(b1 + 128 + 4 * cg);
        const float bv[8] = {c10.x, c10.y, c10.z, c10.w, c11.x, c11.y, c11.z, c11.w};
        #pragma unroll
        for (int i = 0; i < 8; ++i)
            #pragma unroll
            for (int j = 0; j < 4; ++j)
                acc[i][j] = acc2[i][j] + bv[i] + acc[i][j];   // acc := h1
    }

    // ===== LN2 -> relu -> a_t =====
    {
        float s[4] = {0, 0, 0, 0}, q[4] = {0, 0, 0, 0};
        #pragma unroll
        for (int i = 0; i < 8; ++i)
            #pragma unroll
            for (int j = 0; j < 4; ++j) { s[j] += acc[i][j]; q[j] += acc[i][j] * acc[i][j]; }
        #pragma unroll
        for (int m = 1; m < 32; m <<= 1) {
            #pragma unroll
            for (int j = 0; j < 4; ++j) {
                s[j] += __shfl_xor(s[j], m);
                q[j] += __shfl_xor(q[j], m);
            }
        }
        float mu[4], rs[4];
        #pragma unroll
        for (int j = 0; j < 4; ++j) {
            mu[j] = s[j] * (1.f / 256.f);
            float var = q[j] * (1.f / 256.f) - mu[j] * mu[j];
            rs[j] = rsqrtf(var + 1e-5f);
        }
        const float4 g0 = *reinterpret_cast<const float4*>(ln2_g + 4 * cg);
        const float4 g1 = *reinterpret_cast<const float4*>(ln2_g + 128 + 4 * cg);
        const float4 e0 = *reinterpret_cast<const float4*>(ln2_b + 4 * cg);
        const float4 e1 = *reinterpret_cast<const float4*>(ln2_b + 128 + 4 * cg);
        const float gg[8] = {g0.x, g0.y, g0.z, g0.w, g1.x, g1.y, g1.z, g1.w};
        const float bb[8] = {e0.x, e0.y, e0.z, e0.w, e1.x, e1.y, e1.z, e1.w};
        #pragma unroll
        for (int h = 0; h < 2; ++h)
            #pragma unroll
            for (int jj = 0; jj < 4; ++jj) {
                const int i = h * 4 + jj;
                const int qrow = (cg + 32 * h) + 64 * jj;
                float4 av;
                av.x = fmaxf((acc[i][0] - mu[0]) * rs[0] * gg[i] + bb[i], 0.f);
                av.y = fmaxf((acc[i][1] - mu[1]) * rs[1] * gg[i] + bb[i], 0.f);
                av.z = fmaxf((acc[i][2] - mu[2]) * rs[2] * gg[i] + bb[i], 0.f);
                av.w = fmaxf((acc[i][3] - mu[3]) * rs[3] * gg[i] + bb[i], 0.f);
                *reinterpret_cast<float4*>(&sm.u.a_t[qrow][r0]) = av;
            }
    }
    __syncthreads();

    // ============ GEMM3: h2 = a2 @ W2 + b2  ([32,128]) ============
    {
        float acc3[4][4];
        #pragma unroll
        for (int i = 0; i < 4; ++i)
            #pragma unroll
            for (int j = 0; j < 4; ++j) acc3[i][j] = 0.f;
        #pragma unroll 4
        for (int q = 0; q < 256; ++q) {
            const float4 av = *reinterpret_cast<const float4*>(&sm.u.a_t[q][r0]);
            const int k = ((q & 63) << 2) | (q >> 6);
            const float4 w = *reinterpret_cast<const float4*>(W2 + (size_t)k * 128 + 4 * cg);
            const float ar[4] = {av.x, av.y, av.z, av.w};
            const float wc[4] = {w.x, w.y, w.z, w.w};
            #pragma unroll
            for (int i = 0; i < 4; ++i)
                #pragma unroll
                for (int j = 0; j < 4; ++j)
                    acc3[i][j] = fmaf(wc[i], ar[j], acc3[i][j]);
        }
        __syncthreads();   // a_t reads done; h2t overlays
        const float4 b2v = *reinterpret_cast<const float4*>(b2 + 4 * cg);
        const float bv[4] = {b2v.x, b2v.y, b2v.z, b2v.w};
        #pragma unroll
        for (int i = 0; i < 4; ++i) {
            float4 hv;
            hv.x = acc3[i][0] + bv[i];
            hv.y = acc3[i][1] + bv[i];
            hv.z = acc3[i][2] + bv[i];
            hv.w = acc3[i][3] + bv[i];
            *reinterpret_cast<float4*>(&sm.u.p3.h2t[cg + 32 * i][r0]) = hv;
        }
    }
    __syncthreads();

    // ============ GEMM4: logits = (h2 @ W_out + b_out)/T ============
    {
        float acc4[2][4];
        #pragma unroll
        for (int i = 0; i < 2; ++i)
            #pragma unroll
            for (int j = 0; j < 4; ++j) acc4[i][j] = 0.f;
        #pragma unroll 4
        for (int q = 0; q < 128; ++q) {
            const float4 hv = *reinterpret_cast<const float4*>(&sm.u.p3.h2t[q][r0]);
            const int k = ((q & 31) << 2) | (q >> 5);
            const float2 w = *reinterpret_cast<const float2*>(Wo + (size_t)k * 64 + 2 * cg);
            const float hr[4] = {hv.x, hv.y, hv.z, hv.w};
            #pragma unroll
            for (int j = 0; j < 4; ++j) {
                acc4[0][j] = fmaf(w.x, hr[j], acc4[0][j]);
                acc4[1][j] = fmaf(w.y, hr[j], acc4[1][j]);
            }
        }
        const float T = temp[0];
        const float bo0 = bo[2 * cg], bo1 = bo[2 * cg + 1];
        #pragma unroll
        for (int j = 0; j < 4; ++j) {
            sm.u.p3.lgt[r0 + j][2 * cg]     = (acc4[0][j] + bo0) / T;
            sm.u.p3.lgt[r0 + j][2 * cg + 1] = (acc4[1][j] + bo1) / T;
        }
    }
    __syncthreads();

    // ============ softmax + top-8 + contested detection ============
    {
        const int wave = tid >> 6;
        const int lane = tid & 63;
        const float tau = TAU / temp[0];

        for (int j = 0; j < 8; ++j) {
            const int r = wave * 8 + j;
            const float v = sm.u.p3.lgt[r][lane];
            float m = v;
            #pragma unroll
            for (int mk = 32; mk >= 1; mk >>= 1) m = fmaxf(m, __shfl_xor(m, mk));
            float p = expf(v - m);
            float ssum = p;
            #pragma unroll
            for (int mk = 32; mk >= 1; mk >>= 1) ssum += __shfl_xor(ssum, mk);
            const float gp = p / ssum;
            out_gp[(size_t)(row_base + r) * 64 + lane] = gp;

            // top-9 iterative argmax on logits; gap check; ties -> lowest index
            float pv = v;
            int   pi = lane;
            float sum8 = 0.f, myv = 0.f, prev = 0.f;
            int   myi = 0;
            bool  cont = false;
            #pragma unroll
            for (int t = 0; t < 9; ++t) {
                float cv = pv;
                int   ci = pi;
                #pragma unroll
                for (int mk = 32; mk >= 1; mk >>= 1) {
                    const float ov = __shfl_xor(cv, mk);
                    const int   oi = __shfl_xor(ci, mk);
                    if (ov > cv || (ov == cv && oi < ci)) { cv = ov; ci = oi; }
                }
                if (t > 0 && (prev - cv) < tau) cont = true;
                prev = cv;
                if (t < 8) {
                    const float g = __shfl(gp, ci);
                    sum8 += g;
                    if (lane == t)  { myv = g; myi = ci; }
                    if (lane == ci) pv = -3.0e38f;
                }
            }
            if (lane < 8) {
                out_topp[(size_t)(row_base + r) * 8 + lane] = myv / sum8;
                out_topi[(size_t)(row_base + r) * 8 + lane] = (float)myi;
            }
            if (lane == 0 && cont) atomicOr(&cmask, 1u << r);
        }
    }

    // ============ fp64 rescue of contested rows (rare) ============
    __syncthreads();
    unsigned cm = cmask;   // uniform across block
    while (cm) {
        const int r = __ffs(cm) - 1;
        cm &= cm - 1;
        const float* xr = x + (size_t)(row_base + r) * 1024;
        const int c = tid;

        // stage 1: h0[c]
        double a0 = 0.0, a1 = 0.0;
        for (int k = 0; k < 1024; k += 2) {
            a0 = fma((double)xr[k],     (double)W_in[(size_t)k * 256 + c],       a0);
            a1 = fma((double)xr[k + 1], (double)W_in[(size_t)(k + 1) * 256 + c], a1);
        }
        double h = a0 + a1 + (double)b_in[c];
        h = fmax(h, 0.0);
        sm.u.rs.hd0[c] = h;
        __syncthreads();

        // LN1 (redundant serial reduce -> identical result in all threads)
        {
            double s = 0.0, qq = 0.0;
            for (int k = 0; k < 256; ++k) { const double t2 = sm.u.rs.hd0[k]; s += t2; qq += t2 * t2; }
            const double mu = s * (1.0 / 256.0);
            const double var = qq * (1.0 / 256.0) - mu * mu;
            const double rsv = 1.0 / sqrt(var + 1e-5);
            sm.u.rs.a1d[c] = fmax((h - mu) * rsv * (double)ln1_g[c] + (double)ln1_b[c], 0.0);
        }
        __syncthreads();

        // stage 2: h1[c] = a1 @ W1 + b1 + h0
        {
            double a2 = 0.0;
            for (int k = 0; k < 256; ++k)
                a2 = fma(sm.u.rs.a1d[k], (double)W1[(size_t)k * 256 + c], a2);
            const double h1 = a2 + (double)b1[c] + h;
            __syncthreads();           // a1d reads done everywhere
            sm.u.rs.hd0[c] = h1;       // reuse hd0 as h1
            h = h1;
        }
        __syncthreads();

        // LN2
        {
            double s = 0.0, qq = 0.0;
            for (int k = 0; k < 256; ++k) { const double t2 = sm.u.rs.hd0[k]; s += t2; qq += t2 * t2; }
            const double mu = s * (1.0 / 256.0);
            const double var = qq * (1.0 / 256.0) - mu * mu;
            const double rsv = 1.0 / sqrt(var + 1e-5);
            sm.u.rs.a1d[c] = fmax((h - mu) * rsv * (double)ln2_g[c] + (double)ln2_b[c], 0.0);
        }
        __syncthreads();

        // stage 3: h2[c] (c < 128)
        if (c < 128) {
            double a3 = 0.0;
            for (int k = 0; k < 256; ++k)
                a3 = fma(sm.u.rs.a1d[k], (double)W2[(size_t)k * 128 + c], a3);
            sm.u.rs.h2d[c] = a3 + (double)b2[c];
        }
        __syncthreads();

        // stage 4: logits (c < 64)
        if (c < 64) {
            double a4 = 0.0;
            for (int k = 0; k < 128; ++k)
                a4 = fma(sm.u.rs.h2d[k], (double)Wo[(size_t)k * 64 + c], a4);
            sm.u.rs.lgd[c] = (a4 + (double)bo[c]) / (double)temp[0];
        }
        __syncthreads();

        // stage 5: fp64 softmax + top-8 (ranks fp64 probs, exactly like np)
        if (tid < 64) {
            const int lane = tid;
            const double v = sm.u.rs.lgd[lane];
            double m = v;
            #pragma unroll
            for (int mk = 32; mk >= 1; mk >>= 1) m = fmax(m, __shfl_xor(m, mk));
            const double p = exp(v - m);
            double ssum = p;
            #pragma unroll
            for (int mk = 32; mk >= 1; mk >>= 1) ssum += __shfl_xor(ssum, mk);
            const double gp = p / ssum;
            out_gp[(size_t)(row_base + r) * 64 + lane] = (float)gp;

            double pv = gp;
            int    pi = lane;
            double sum8 = 0.0, myv = 0.0;
            int    myi = 0;
            #pragma unroll
            for (int t = 0; t < 8; ++t) {
                double cv = pv;
                int    ci = pi;
                #pragma unroll
                for (int mk = 32; mk >= 1; mk >>= 1) {
                    const double ov = __shfl_xor(cv, mk);
                    const int    oi = __shfl_xor(ci, mk);
                    if (ov > cv || (ov == cv && oi < ci)) { cv = ov; ci = oi; }
                }
                sum8 += cv;
                if (lane == t)  { myv = cv; myi = ci; }
                if (lane == ci) pv = -1.0;
            }
            if (lane < 8) {
                out_topp[(size_t)(row_base + r) * 8 + lane] = (float)(myv / sum8);
                out_topi[(size_t)(row_base + r) * 8 + lane] = (float)myi;
            }
        }
    }
}

extern "C" void kernel_launch(void* const* d_in, const int* in_sizes, int n_in,
                              void* d_out, int out_size, void* d_ws, size_t ws_size,
                              hipStream_t stream) {
    const float* x     = (const float*)d_in[0];
    const float* W_in  = (const float*)d_in[1];
    const float* b_in  = (const float*)d_in[2];
    const float* ln1_g = (const float*)d_in[3];
    const float* ln1_b = (const float*)d_in[4];
    const float* W1    = (const float*)d_in[5];
    const float* b1    = (const float*)d_in[6];
    const float* ln2_g = (const float*)d_in[7];
    const float* ln2_b = (const float*)d_in[8];
    const float* W2    = (const float*)d_in[9];
    const float* b2    = (const float*)d_in[10];
    const float* Wo    = (const float*)d_in[11];
    const float* bo    = (const float*)d_in[12];
    const float* temp  = (const float*)d_in[13];

    gating_fused_f32<<<dim3(65536 / ROWS), dim3(NTHREADS), 0, stream>>>(
        x, W_in, b_in, ln1_g, ln1_b, W1, b1, ln2_g, ln2_b, W2, b2, Wo, bo, temp,
        (float*)d_out);
}